// Round 10
// baseline (285.983 us; speedup 1.0000x reference)
//
#include <hip/hip_runtime.h>
#include <math.h>

#define BQ 64
#define TBI 3000
#define DBI 128
#define TSW 375
#define TS1 188
#define DSW 192
#define NF 300
#define DMODEL 512
#define EPSLN 1e-5f

typedef __bf16 bf16x8 __attribute__((ext_vector_type(8)));
typedef float f32x4 __attribute__((ext_vector_type(4)));

__device__ __forceinline__ unsigned short f2bf(float f) {
    unsigned u = __float_as_uint(f);
    unsigned r = (u + 0x7FFFu + ((u >> 16) & 1u)) >> 16;
    return (unsigned short)r;
}

#define ALPHA_BLOCKS 24000   // (BQ*TBI)/8

// ---------------- Kernel A+prep merged; prep swizzle coalesced-read/scattered-write
__global__ __launch_bounds__(256) void k_alpha_prep(
    const float* __restrict__ fs, const float* __restrict__ conv_w,
    const float* __restrict__ ln_g, const float* __restrict__ ln_b,
    const float* __restrict__ wp_w, const float* __restrict__ wp_b,
    float* __restrict__ alpha_out,
    const float* __restrict__ f0w, const float* __restrict__ f1w,
    const float* __restrict__ tw, const float* __restrict__ aw, const float* __restrict__ bw,
    const float* __restrict__ f0b, const float* __restrict__ f1b,
    const float* __restrict__ tb, const float* __restrict__ apb, const float* __restrict__ bpb,
    unsigned short* __restrict__ Wg, unsigned short* __restrict__ Wb,
    unsigned short* __restrict__ W2,
    float* __restrict__ gbias, float* __restrict__ bbias, float* __restrict__ bias2,
    float* __restrict__ qtyo)
{
    if (blockIdx.x >= ALPHA_BLOCKS) {
        int pbid = blockIdx.x - ALPHA_BLOCKS;
        if (pbid == 1216) {
            for (int c = threadIdx.x; c < 512; c += 256) {
                if (c < 384) {
                    gbias[c] = c < 192 ? f0b[c] : f1b[c - 192];
                    bbias[c] = c < 192 ? f0b[c + 192] : f1b[c - 192 + 192];
                }
                bias2[c] = tb[c] + apb[c] + bpb[c];
            }
            if (threadIdx.x == 0) qtyo[0] = 0.f;
            return;
        }
        int i = pbid * 256 + threadIdx.x;
        if (i < 49152) {                       // film: linear (k,n), k in [0,128), n in [0,384)
            int k = i / 384;
            int n = i - k * 384;
            float g, b;
            if (n < 192) { g = f0w[k * 384 + n]; b = f0w[k * 384 + n + 192]; }
            else         { g = f1w[k * 384 + (n - 192)]; b = f1w[k * 384 + n]; }
            int kt = k >> 5, j = k & 7;
            int lane = ((k >> 3) & 3) * 16 + (n & 15);
            int nt = n >> 4;
            int out = ((nt * 4 + kt) * 64 + lane) * 8 + j;
            Wg[out] = f2bf(g); Wb[out] = f2bf(b);
        } else {                               // W2: linear (k,n), k in [0,512), n in [0,512)
            int ii = i - 49152;
            int k = ii >> 9, n = ii & 511;
            float v;
            if (k < 128)      v = tw[k * 512 + n];
            else if (k < 320) v = aw[(k - 128) * 512 + n];
            else              v = bw[(k - 320) * 512 + n];
            int kt = k >> 5, j = k & 7;
            int lane = ((k >> 3) & 3) * 16 + (n & 15);
            int nt = n >> 4;
            int out = ((nt * 16 + kt) * 64 + lane) * 8 + j;
            W2[out] = f2bf(v);
        }
        return;
    }
    int wave = threadIdx.x >> 6, lane = threadIdx.x & 63;
    int l = lane & 31;
    long g = (long)blockIdx.x * 8 + wave * 2 + (lane >> 5);
    const float* row = fs + g * DBI;
    float4 f  = *(const float4*)&row[4 * l];
    float4 cw = *(const float4*)&conv_w[4 * l];
    float4 x; x.x = f.x * cw.x; x.y = f.y * cw.y; x.z = f.z * cw.z; x.w = f.w * cw.w;
    float s = x.x + x.y + x.z + x.w;
    for (int m = 16; m >= 1; m >>= 1) s += __shfl_xor(s, m, 64);
    float mu = s * (1.0f / 128.0f);
    float4 d; d.x = x.x - mu; d.y = x.y - mu; d.z = x.z - mu; d.w = x.w - mu;
    float q = d.x * d.x + d.y * d.y + d.z * d.z + d.w * d.w;
    for (int m = 16; m >= 1; m >>= 1) q += __shfl_xor(q, m, 64);
    float var = q * (1.0f / 128.0f);
    float rs = rsqrtf(var + EPSLN);
    float4 lg = *(const float4*)&ln_g[4 * l];
    float4 lb = *(const float4*)&ln_b[4 * l];
    float4 wp = *(const float4*)&wp_w[4 * l];
    float z = (d.x * rs * lg.x + lb.x) * wp.x + (d.y * rs * lg.y + lb.y) * wp.y
            + (d.z * rs * lg.z + lb.z) * wp.z + (d.w * rs * lg.w + lb.w) * wp.w;
    for (int m = 16; m >= 1; m >>= 1) z += __shfl_xor(z, m, 64);
    z += wp_b[0];
    float a = 4.0f / (1.0f + expf(-z));
    if (l == 0) alpha_out[g] = a;
}

// ---------------- Kernel B: sums (f64, wave-shuffle) + scan + searchsorted + ff + qty
__global__ __launch_bounds__(1024) void k_scan4(
    const float* __restrict__ alpha, const int* __restrict__ tlen,
    float2* __restrict__ params, float* __restrict__ qtyo,
    float2* __restrict__ c2, float* __restrict__ tcont, int* __restrict__ ffout)
{
    __shared__ float2 sc[TBI];
    __shared__ float2 part[2][1024];
    __shared__ double wpart[16];
    int b = blockIdx.x, tid = threadIdx.x;
    int wv = tid >> 6, ln = tid & 63;
    const float* ar = alpha + (long)b * TBI;
    double s = 0.0;
    for (int t = tid; t < TBI; t += 1024) s += (double)ar[t];
    for (int m = 32; m >= 1; m >>= 1) s += __shfl_xor(s, m, 64);
    if (ln == 0) wpart[wv] = s;
    __syncthreads();
    if (wv == 0) {
        double d = (ln < 16) ? wpart[ln] : 0.0;
        for (int m = 8; m >= 1; m >>= 1) d += __shfl_xor(d, m, 64);
        if (ln == 0) wpart[0] = d;
    }
    __syncthreads();
    double sum_a = wpart[0];
    __syncthreads();
    double tgt = (double)tlen[b];
    double sa = sum_a < 1e-8 ? 1e-8 : sum_a;
    float r = (float)(tgt / sa);
    double s2 = 0.0;
    for (int t = tid; t < TBI; t += 1024) s2 += (double)(ar[t] * r);
    for (int m = 32; m >= 1; m >>= 1) s2 += __shfl_xor(s2, m, 64);
    if (ln == 0) wpart[wv] = s2;
    __syncthreads();
    if (wv == 0) {
        double d = (ln < 16) ? wpart[ln] : 0.0;
        for (int m = 8; m >= 1; m >>= 1) d += __shfl_xor(d, m, 64);
        if (ln == 0) wpart[0] = d;
    }
    __syncthreads();
    float sum_cif = (float)wpart[0];
    float cs = ceilf(sum_cif); if (cs < 1.0f) cs = 1.0f;
    float thr = sum_cif / cs;
    float rthr = 1.0f / thr;
    if (tid == 0) {
        params[b] = make_float2(r, thr);
        atomicAdd(qtyo, (float)fabs(sum_a - tgt) * (1.0f / (float)BQ));
    }
    // ---- scan: byte-identical Hillis-Steele (feeds searchsorted boundaries)
    int base = tid * 3;
    float2 run = make_float2(0.f, 0.f);
    if (base < TBI) {
        for (int j = 0; j < 3; ++j) {
            int t = base + j;
            float ac = ar[t] * r;
            run.x += ac * rthr; run.y += ac;
            sc[t] = run;
        }
    }
    part[0][tid] = (base < TBI) ? run : make_float2(0.f, 0.f);
    __syncthreads();
    int srcb = 0;
    for (int d = 1; d < 1024; d <<= 1) {
        float2 v = part[srcb][tid];
        if (tid >= d) { float2 u = part[srcb][tid - d]; v.x += u.x; v.y += u.y; }
        part[srcb ^ 1][tid] = v;
        srcb ^= 1;
        __syncthreads();
    }
    if (base < TBI && tid > 0) {
        float2 off = part[srcb][tid - 1];
        for (int j = 0; j < 3; ++j) { sc[base + j].x += off.x; sc[base + j].y += off.y; }
    }
    __syncthreads();
    for (int t = tid; t < TBI; t += 1024) {
        float ac = ar[t] * r;
        c2[(long)b * TBI + t] = make_float2(sc[t].x, ac);
    }
    if (tid < NF) {
        float v = (float)(tid + 1) * thr;
        int lo = 0, hi = TBI;
        while (lo < hi) { int mid = (lo + hi) >> 1; if (sc[mid].y < v) lo = mid + 1; else hi = mid; }
        int ff = lo; if (ff > TBI - 1) ff = TBI - 1;
        ffout[b * NF + tid] = ff;
        int tl = ff - 1; if (tl < 0) tl = 0;
        float cum_at = sc[tl].y;
        float a_at = ar[ff] * r;
        if (a_at < 1e-8f) a_at = 1e-8f;
        float tc = (float)tl + (v - cum_at) / a_at;
        tc = fminf(fmaxf(tc, 0.0f), (float)(TBI - 1));
        tcont[b * NF + tid] = tc;
    }
}

// ---------------- Kernel D: CIF, one wave per token; 2-frame unrolled (same accum order)
__global__ __launch_bounds__(256) void k_cif5(
    const float* __restrict__ fs, const float2* __restrict__ c2,
    const int* __restrict__ ffA, const float2* __restrict__ params,
    unsigned short* __restrict__ at)
{
    int wid = threadIdx.x >> 6, lane = threadIdx.x & 63;
    int wg = blockIdx.x * 4 + wid;          // 0..19199
    int b = wg / NF, j = wg - b * NF;
    const int* ffb = ffA + b * NF;
    int s = (j == 0) ? 0 : ffb[j - 1];
    int e = (j == NF - 1) ? (TBI - 1) : ffb[j];
    float thr = params[b].y;
    float rthr = 1.0f / thr;
    const float2* cb = c2 + (long)b * TBI;
    const float* fb = fs + (long)b * TBI * DBI;
    float a0 = 0.f, a1 = 0.f;
    #define CIF_BODY(T) do { \
        float2 v = cb[T]; \
        float2 h = *(const float2*)&fb[(long)(T) * DBI + 2 * lane]; \
        float c = v.x, ac = v.y; \
        float av = ac * rthr; \
        float prev = c - av; \
        float kp = floorf(prev), kc = floorf(c); \
        bool fired = kc > kp; \
        float w_lo = fired ? (kp + 1.0f - prev) * thr : ac; \
        float w_hi = fired ? (c - kc) * thr : 0.0f; \
        int ip = (int)kp; if (ip > NF - 1) ip = NF - 1; if (ip < 0) ip = 0; \
        int ic = (int)kc; if (ic > NF - 1) ic = NF - 1; if (ic < 0) ic = 0; \
        if (ip == j) { a0 += w_lo * h.x; a1 += w_lo * h.y; } \
        if (fired && ic == j) { a0 += w_hi * h.x; a1 += w_hi * h.y; } \
    } while (0)
    int t = s;
    for (; t + 1 <= e; t += 2) { CIF_BODY(t); CIF_BODY(t + 1); }
    if (t <= e) CIF_BODY(t);
    #undef CIF_BODY
    unsigned short* ab = at + (long)b * NF * DBI;
    *(unsigned*)&ab[j * DBI + 2 * lane] = (unsigned)f2bf(a0) | ((unsigned)f2bf(a1) << 16);
}

// ---------------- Kernel E1: film GEMM + interp -> Xg[19200][384] bf16.
// 16 rows/block, 1200 blocks, 4 waves; no trailing barrier: gathers from all
// blocks overlap. Arithmetic/order identical to fused emb9 phase 1.
#define FROWS 16
__global__ __launch_bounds__(256, 4) void k_film(
    const unsigned short* __restrict__ atb, const float* __restrict__ tcont,
    const float* __restrict__ src0, const float* __restrict__ src1,
    const unsigned short* __restrict__ Wg, const unsigned short* __restrict__ Wb,
    const float* __restrict__ gbias, const float* __restrict__ bbias,
    unsigned short* __restrict__ Xg)
{
    __shared__ __align__(16) unsigned short X[FROWS][136];
    __shared__ float s_w0[FROWS], s_w1[FROWS];
    __shared__ int s_lo0[FROWS], s_lo1[FROWS], s_b[FROWS];
    int tid = threadIdx.x;
    int wave = tid >> 6, lane = tid & 63;
    long r0 = (long)blockIdx.x * FROWS;
    {
        int r = tid >> 4, k8 = (tid & 15) * 8;     // 256 thr = 16 rows x 16 chunks
        *(uint4*)&X[r][k8] = *(const uint4*)&atb[(r0 + r) * DBI + k8];
    }
    if (tid < FROWS) {
        long g = r0 + tid;
        s_b[tid] = (int)(g / NF);
        float tc = tcont[g];
        float t0 = tc * ((float)TSW / 3000.0f);
        int lo0 = (int)t0; if (lo0 > TSW - 2) lo0 = TSW - 2; if (lo0 < 0) lo0 = 0;
        s_lo0[tid] = lo0; s_w0[tid] = t0 - (float)lo0;
        float t1 = tc * ((float)TS1 / 3000.0f);
        int lo1 = (int)t1; if (lo1 > TS1 - 2) lo1 = TS1 - 2; if (lo1 < 0) lo1 = 0;
        s_lo1[tid] = lo1; s_w1[tid] = t1 - (float)lo1;
    }
    __syncthreads();
    int mrow = lane & 15, quad = lane >> 4;
    for (int i = 0; i < 6; ++i) {
        int nt = wave + 4 * i;
        f32x4 ag0 = {0,0,0,0}, ab0 = {0,0,0,0};
        #pragma unroll
        for (int kt = 0; kt < 4; ++kt) {
            bf16x8 a0 = *(const bf16x8*)&X[mrow][kt * 32 + quad * 8];
            bf16x8 bg = *(const bf16x8*)&Wg[(((nt * 4 + kt) * 64) + lane) * 8];
            bf16x8 bb = *(const bf16x8*)&Wb[(((nt * 4 + kt) * 64) + lane) * 8];
            ag0 = __builtin_amdgcn_mfma_f32_16x16x32_bf16(a0, bg, ag0, 0, 0, 0);
            ab0 = __builtin_amdgcn_mfma_f32_16x16x32_bf16(a0, bb, ab0, 0, 0, 0);
        }
        int c = nt * 16 + mrow;
        bool sel = c >= DSW;
        int cc = sel ? c - DSW : c;
        const float* S = sel ? src1 : src0;
        int Ts = sel ? TS1 : TSW;
        float gb = gbias[c], bbv = bbias[c];
        #pragma unroll
        for (int q = 0; q < 4; ++q) {
            int r = quad * 4 + q;
            int b = s_b[r];
            int lo = sel ? s_lo1[r] : s_lo0[r];
            float w = sel ? s_w1[r] : s_w0[r];
            const float* Sp = S + ((long)b * Ts + lo) * DSW + cc;
            float pv = (1.0f - w) * Sp[0] + w * Sp[DSW];
            Xg[(r0 + r) * 384 + c] = f2bf((ag0[q] + gb) * pv + (ab0[q] + bbv));
        }
    }
}

// ---------------- Kernel E2: pure GEMM embs[19200,512] = [at|Xg] @ W2 + bias2.
// Exactly emb9's phase 2 ((256,3), acc[2][8], 600 blocks); LDS staged from at+Xg.
#define EROWS 32
__global__ __launch_bounds__(256, 3) void k_gemm2(
    const unsigned short* __restrict__ atb, const unsigned short* __restrict__ Xg,
    const unsigned short* __restrict__ W2, const float* __restrict__ bias2,
    float* __restrict__ embs)
{
    __shared__ __align__(16) unsigned short X[EROWS][520];
    int tid = threadIdx.x;
    int wave = tid >> 6, lane = tid & 63;
    long r0 = (long)blockIdx.x * EROWS;
    for (int idx = tid; idx < 512; idx += 256) {       // cols 0..127 from at
        int r = idx >> 4, k8 = (idx & 15) * 8;
        *(uint4*)&X[r][k8] = *(const uint4*)&atb[(r0 + r) * DBI + k8];
    }
    for (int idx = tid; idx < 1536; idx += 256) {      // cols 128..511 from Xg
        int r = idx / 48, c8 = (idx - r * 48) * 8;
        *(uint4*)&X[r][128 + c8] = *(const uint4*)&Xg[(r0 + r) * 384 + c8];
    }
    __syncthreads();
    int mrow = lane & 15, quad = lane >> 4;
    f32x4 acc[2][8];
    #pragma unroll
    for (int h = 0; h < 2; ++h)
        #pragma unroll
        for (int n = 0; n < 8; ++n) acc[h][n] = (f32x4){0, 0, 0, 0};
    for (int kt = 0; kt < 16; ++kt) {
        bf16x8 a0 = *(const bf16x8*)&X[mrow][kt * 32 + quad * 8];
        bf16x8 a1 = *(const bf16x8*)&X[mrow + 16][kt * 32 + quad * 8];
        #pragma unroll
        for (int n = 0; n < 8; ++n) {
            int nt = wave * 8 + n;
            bf16x8 bfv = *(const bf16x8*)&W2[((nt * 16 + kt) * 64 + lane) * 8];
            acc[0][n] = __builtin_amdgcn_mfma_f32_16x16x32_bf16(a0, bfv, acc[0][n], 0, 0, 0);
            acc[1][n] = __builtin_amdgcn_mfma_f32_16x16x32_bf16(a1, bfv, acc[1][n], 0, 0, 0);
        }
    }
    #pragma unroll
    for (int n = 0; n < 8; ++n) {
        int cbase = (wave * 8 + n) * 16 + mrow;
        float bv = bias2[cbase];
        #pragma unroll
        for (int q = 0; q < 4; ++q) {
            embs[(r0 + quad * 4 + q) * DMODEL + cbase] = acc[0][n][q] + bv;
            embs[(r0 + 16 + quad * 4 + q) * DMODEL + cbase] = acc[1][n][q] + bv;
        }
    }
}

extern "C" void kernel_launch(void* const* d_in, const int* in_sizes, int n_in,
                              void* d_out, int out_size, void* d_ws, size_t ws_size,
                              hipStream_t stream)
{
    const float* fs     = (const float*)d_in[0];
    const float* src0   = (const float*)d_in[1];
    const float* src1   = (const float*)d_in[2];
    const int*   tlen   = (const int*)d_in[3];
    const float* conv_w = (const float*)d_in[4];
    const float* ln_g   = (const float*)d_in[5];
    const float* ln_b   = (const float*)d_in[6];
    const float* wp_w   = (const float*)d_in[7];
    const float* wp_b   = (const float*)d_in[8];
    const float* f0w    = (const float*)d_in[9];
    const float* f0b    = (const float*)d_in[10];
    const float* f1w    = (const float*)d_in[11];
    const float* f1b    = (const float*)d_in[12];
    const float* tw     = (const float*)d_in[13];
    const float* tb     = (const float*)d_in[14];
    const float* aw     = (const float*)d_in[15];
    const float* apb    = (const float*)d_in[16];
    const float* bw     = (const float*)d_in[17];
    const float* bpb    = (const float*)d_in[18];

    float* embs  = (float*)d_out;
    float* alpha = embs + (long)BQ * NF * DMODEL;
    float* qtyo  = alpha + (long)BQ * TBI;

    char* ws = (char*)d_ws;
    size_t off = 0;
    unsigned short* at = (unsigned short*)(ws + off); off += 4915200;   // [B,NF,128] bf16
    float2* c2     = (float2*)(ws + off); off += 1536000;
    float*  tcont  = (float*)(ws + off);  off += 76800;
    int*    ffA    = (int*)(ws + off);    off += 76800;
    float2* params = (float2*)(ws + off); off += 512;
    unsigned short* Wg = (unsigned short*)(ws + off); off += 98304;
    unsigned short* Wb = (unsigned short*)(ws + off); off += 98304;
    unsigned short* W2 = (unsigned short*)(ws + off); off += 524288;
    float* gbias = (float*)(ws + off); off += 1536;
    float* bbias = (float*)(ws + off); off += 1536;
    float* bias2 = (float*)(ws + off); off += 2048;
    unsigned short* Xg = (unsigned short*)(ws + off); off += 14745600;  // [19200][384] bf16

    k_alpha_prep<<<ALPHA_BLOCKS + 1217, 256, 0, stream>>>(
        fs, conv_w, ln_g, ln_b, wp_w, wp_b, alpha,
        f0w, f1w, tw, aw, bw, f0b, f1b, tb, apb, bpb,
        Wg, Wb, W2, gbias, bbias, bias2, qtyo);
    k_scan4<<<BQ, 1024, 0, stream>>>(alpha, tlen, params, qtyo, c2, tcont, ffA);
    k_cif5<<<(BQ * NF) / 4, 256, 0, stream>>>(fs, c2, ffA, params, at);
    k_film<<<(BQ * NF) / FROWS, 256, 0, stream>>>(at, tcont, src0, src1,
                                                  Wg, Wb, gbias, bbias, Xg);
    k_gemm2<<<(BQ * NF) / EROWS, 256, 0, stream>>>(at, Xg, W2, bias2, embs);
}

// Round 11
// 266.036 us; speedup vs baseline: 1.0750x; 1.0750x over previous
//
#include <hip/hip_runtime.h>
#include <math.h>

#define BQ 64
#define TBI 3000
#define DBI 128
#define TSW 375
#define TS1 188
#define DSW 192
#define NF 300
#define DMODEL 512
#define EPSLN 1e-5f

typedef __bf16 bf16x8 __attribute__((ext_vector_type(8)));
typedef float f32x4 __attribute__((ext_vector_type(4)));

__device__ __forceinline__ unsigned short f2bf(float f) {
    unsigned u = __float_as_uint(f);
    unsigned r = (u + 0x7FFFu + ((u >> 16) & 1u)) >> 16;
    return (unsigned short)r;
}

#define ALPHA_BLOCKS 24000   // (BQ*TBI)/8

// ---------------- Kernel A+prep merged; prep swizzle coalesced-read/scattered-write
// (validated byte-identical vs original swizzle in r8/r10; ~3us cheaper than strided read)
__global__ __launch_bounds__(256) void k_alpha_prep(
    const float* __restrict__ fs, const float* __restrict__ conv_w,
    const float* __restrict__ ln_g, const float* __restrict__ ln_b,
    const float* __restrict__ wp_w, const float* __restrict__ wp_b,
    float* __restrict__ alpha_out,
    const float* __restrict__ f0w, const float* __restrict__ f1w,
    const float* __restrict__ tw, const float* __restrict__ aw, const float* __restrict__ bw,
    const float* __restrict__ f0b, const float* __restrict__ f1b,
    const float* __restrict__ tb, const float* __restrict__ apb, const float* __restrict__ bpb,
    unsigned short* __restrict__ Wg, unsigned short* __restrict__ Wb,
    unsigned short* __restrict__ W2,
    float* __restrict__ gbias, float* __restrict__ bbias, float* __restrict__ bias2,
    float* __restrict__ qtyo)
{
    if (blockIdx.x >= ALPHA_BLOCKS) {
        int pbid = blockIdx.x - ALPHA_BLOCKS;
        if (pbid == 1216) {
            for (int c = threadIdx.x; c < 512; c += 256) {
                if (c < 384) {
                    gbias[c] = c < 192 ? f0b[c] : f1b[c - 192];
                    bbias[c] = c < 192 ? f0b[c + 192] : f1b[c - 192 + 192];
                }
                bias2[c] = tb[c] + apb[c] + bpb[c];
            }
            if (threadIdx.x == 0) qtyo[0] = 0.f;
            return;
        }
        int i = pbid * 256 + threadIdx.x;
        if (i < 49152) {                       // film: linear (k,n), k in [0,128), n in [0,384)
            int k = i / 384;
            int n = i - k * 384;
            float g, b;
            if (n < 192) { g = f0w[k * 384 + n]; b = f0w[k * 384 + n + 192]; }
            else         { g = f1w[k * 384 + (n - 192)]; b = f1w[k * 384 + n]; }
            int kt = k >> 5, j = k & 7;
            int lane = ((k >> 3) & 3) * 16 + (n & 15);
            int nt = n >> 4;
            int out = ((nt * 4 + kt) * 64 + lane) * 8 + j;
            Wg[out] = f2bf(g); Wb[out] = f2bf(b);
        } else {                               // W2: linear (k,n), k in [0,512), n in [0,512)
            int ii = i - 49152;
            int k = ii >> 9, n = ii & 511;
            float v;
            if (k < 128)      v = tw[k * 512 + n];
            else if (k < 320) v = aw[(k - 128) * 512 + n];
            else              v = bw[(k - 320) * 512 + n];
            int kt = k >> 5, j = k & 7;
            int lane = ((k >> 3) & 3) * 16 + (n & 15);
            int nt = n >> 4;
            int out = ((nt * 16 + kt) * 64 + lane) * 8 + j;
            W2[out] = f2bf(v);
        }
        return;
    }
    int wave = threadIdx.x >> 6, lane = threadIdx.x & 63;
    int l = lane & 31;
    long g = (long)blockIdx.x * 8 + wave * 2 + (lane >> 5);
    const float* row = fs + g * DBI;
    float4 f  = *(const float4*)&row[4 * l];
    float4 cw = *(const float4*)&conv_w[4 * l];
    float4 x; x.x = f.x * cw.x; x.y = f.y * cw.y; x.z = f.z * cw.z; x.w = f.w * cw.w;
    float s = x.x + x.y + x.z + x.w;
    for (int m = 16; m >= 1; m >>= 1) s += __shfl_xor(s, m, 64);
    float mu = s * (1.0f / 128.0f);
    float4 d; d.x = x.x - mu; d.y = x.y - mu; d.z = x.z - mu; d.w = x.w - mu;
    float q = d.x * d.x + d.y * d.y + d.z * d.z + d.w * d.w;
    for (int m = 16; m >= 1; m >>= 1) q += __shfl_xor(q, m, 64);
    float var = q * (1.0f / 128.0f);
    float rs = rsqrtf(var + EPSLN);
    float4 lg = *(const float4*)&ln_g[4 * l];
    float4 lb = *(const float4*)&ln_b[4 * l];
    float4 wp = *(const float4*)&wp_w[4 * l];
    float z = (d.x * rs * lg.x + lb.x) * wp.x + (d.y * rs * lg.y + lb.y) * wp.y
            + (d.z * rs * lg.z + lb.z) * wp.z + (d.w * rs * lg.w + lb.w) * wp.w;
    for (int m = 16; m >= 1; m >>= 1) z += __shfl_xor(z, m, 64);
    z += wp_b[0];
    float a = 4.0f / (1.0f + expf(-z));
    if (l == 0) alpha_out[g] = a;
}

// ---------------- Kernel B: sums (f64, wave-shuffle) + scan + searchsorted + ff + qty
__global__ __launch_bounds__(1024) void k_scan4(
    const float* __restrict__ alpha, const int* __restrict__ tlen,
    float2* __restrict__ params, float* __restrict__ qtyo,
    float2* __restrict__ c2, float* __restrict__ tcont, int* __restrict__ ffout)
{
    __shared__ float2 sc[TBI];
    __shared__ float2 part[2][1024];
    __shared__ double wpart[16];
    int b = blockIdx.x, tid = threadIdx.x;
    int wv = tid >> 6, ln = tid & 63;
    const float* ar = alpha + (long)b * TBI;
    double s = 0.0;
    for (int t = tid; t < TBI; t += 1024) s += (double)ar[t];
    for (int m = 32; m >= 1; m >>= 1) s += __shfl_xor(s, m, 64);
    if (ln == 0) wpart[wv] = s;
    __syncthreads();
    if (wv == 0) {
        double d = (ln < 16) ? wpart[ln] : 0.0;
        for (int m = 8; m >= 1; m >>= 1) d += __shfl_xor(d, m, 64);
        if (ln == 0) wpart[0] = d;
    }
    __syncthreads();
    double sum_a = wpart[0];
    __syncthreads();
    double tgt = (double)tlen[b];
    double sa = sum_a < 1e-8 ? 1e-8 : sum_a;
    float r = (float)(tgt / sa);
    double s2 = 0.0;
    for (int t = tid; t < TBI; t += 1024) s2 += (double)(ar[t] * r);
    for (int m = 32; m >= 1; m >>= 1) s2 += __shfl_xor(s2, m, 64);
    if (ln == 0) wpart[wv] = s2;
    __syncthreads();
    if (wv == 0) {
        double d = (ln < 16) ? wpart[ln] : 0.0;
        for (int m = 8; m >= 1; m >>= 1) d += __shfl_xor(d, m, 64);
        if (ln == 0) wpart[0] = d;
    }
    __syncthreads();
    float sum_cif = (float)wpart[0];
    float cs = ceilf(sum_cif); if (cs < 1.0f) cs = 1.0f;
    float thr = sum_cif / cs;
    float rthr = 1.0f / thr;
    if (tid == 0) {
        params[b] = make_float2(r, thr);
        atomicAdd(qtyo, (float)fabs(sum_a - tgt) * (1.0f / (float)BQ));
    }
    // ---- scan: byte-identical Hillis-Steele (feeds searchsorted boundaries)
    int base = tid * 3;
    float2 run = make_float2(0.f, 0.f);
    if (base < TBI) {
        for (int j = 0; j < 3; ++j) {
            int t = base + j;
            float ac = ar[t] * r;
            run.x += ac * rthr; run.y += ac;
            sc[t] = run;
        }
    }
    part[0][tid] = (base < TBI) ? run : make_float2(0.f, 0.f);
    __syncthreads();
    int srcb = 0;
    for (int d = 1; d < 1024; d <<= 1) {
        float2 v = part[srcb][tid];
        if (tid >= d) { float2 u = part[srcb][tid - d]; v.x += u.x; v.y += u.y; }
        part[srcb ^ 1][tid] = v;
        srcb ^= 1;
        __syncthreads();
    }
    if (base < TBI && tid > 0) {
        float2 off = part[srcb][tid - 1];
        for (int j = 0; j < 3; ++j) { sc[base + j].x += off.x; sc[base + j].y += off.y; }
    }
    __syncthreads();
    for (int t = tid; t < TBI; t += 1024) {
        float ac = ar[t] * r;
        c2[(long)b * TBI + t] = make_float2(sc[t].x, ac);
    }
    if (tid < NF) {
        float v = (float)(tid + 1) * thr;
        int lo = 0, hi = TBI;
        while (lo < hi) { int mid = (lo + hi) >> 1; if (sc[mid].y < v) lo = mid + 1; else hi = mid; }
        int ff = lo; if (ff > TBI - 1) ff = TBI - 1;
        ffout[b * NF + tid] = ff;
        int tl = ff - 1; if (tl < 0) tl = 0;
        float cum_at = sc[tl].y;
        float a_at = ar[ff] * r;
        if (a_at < 1e-8f) a_at = 1e-8f;
        float tc = (float)tl + (v - cum_at) / a_at;
        tc = fminf(fmaxf(tc, 0.0f), (float)(TBI - 1));
        tcont[b * NF + tid] = tc;
    }
}

// ---------------- Kernel D: CIF, one wave per token; 2-frame unrolled (same accum order)
__global__ __launch_bounds__(256) void k_cif5(
    const float* __restrict__ fs, const float2* __restrict__ c2,
    const int* __restrict__ ffA, const float2* __restrict__ params,
    unsigned short* __restrict__ at)
{
    int wid = threadIdx.x >> 6, lane = threadIdx.x & 63;
    int wg = blockIdx.x * 4 + wid;          // 0..19199
    int b = wg / NF, j = wg - b * NF;
    const int* ffb = ffA + b * NF;
    int s = (j == 0) ? 0 : ffb[j - 1];
    int e = (j == NF - 1) ? (TBI - 1) : ffb[j];
    float thr = params[b].y;
    float rthr = 1.0f / thr;
    const float2* cb = c2 + (long)b * TBI;
    const float* fb = fs + (long)b * TBI * DBI;
    float a0 = 0.f, a1 = 0.f;
    #define CIF_BODY(T) do { \
        float2 v = cb[T]; \
        float2 h = *(const float2*)&fb[(long)(T) * DBI + 2 * lane]; \
        float c = v.x, ac = v.y; \
        float av = ac * rthr; \
        float prev = c - av; \
        float kp = floorf(prev), kc = floorf(c); \
        bool fired = kc > kp; \
        float w_lo = fired ? (kp + 1.0f - prev) * thr : ac; \
        float w_hi = fired ? (c - kc) * thr : 0.0f; \
        int ip = (int)kp; if (ip > NF - 1) ip = NF - 1; if (ip < 0) ip = 0; \
        int ic = (int)kc; if (ic > NF - 1) ic = NF - 1; if (ic < 0) ic = 0; \
        if (ip == j) { a0 += w_lo * h.x; a1 += w_lo * h.y; } \
        if (fired && ic == j) { a0 += w_hi * h.x; a1 += w_hi * h.y; } \
    } while (0)
    int t = s;
    for (; t + 1 <= e; t += 2) { CIF_BODY(t); CIF_BODY(t + 1); }
    if (t <= e) CIF_BODY(t);
    #undef CIF_BODY
    unsigned short* ab = at + (long)b * NF * DBI;
    *(unsigned*)&ab[j * DBI + 2 * lane] = (unsigned)f2bf(a0) | ((unsigned)f2bf(a1) << 16);
}

// ---------------- Kernel E (MFMA): FiLM + interp + projections; EROWS=32, 600 blocks,
// 256 threads (4 waves), launch_bounds(256,3). Measured-best emb config (41.5us):
// all co-resident, no spill. Six structural variants (512-thr fused, gather-hoist,
// reg-dbuf, (256,4) spill, kernel split) measured equal-or-worse -> latency floor.
#define EROWS 32
__global__ __launch_bounds__(256, 3) void k_emb9(
    const unsigned short* __restrict__ atb, const float* __restrict__ tcont,
    const float* __restrict__ src0, const float* __restrict__ src1,
    const unsigned short* __restrict__ Wg, const unsigned short* __restrict__ Wb,
    const unsigned short* __restrict__ W2,
    const float* __restrict__ gbias, const float* __restrict__ bbias,
    const float* __restrict__ bias2, float* __restrict__ embs)
{
    __shared__ __align__(16) unsigned short X[EROWS][520];
    __shared__ float s_w0[EROWS], s_w1[EROWS];
    __shared__ int s_lo0[EROWS], s_lo1[EROWS], s_b[EROWS];
    int tid = threadIdx.x;
    int wave = tid >> 6, lane = tid & 63;
    long r0 = (long)blockIdx.x * EROWS;
    for (int idx = tid; idx < 512; idx += 256) {   // 32 rows x 16 chunks of 8 bf16
        int r = idx >> 4, k8 = (idx & 15) * 8;
        *(uint4*)&X[r][k8] = *(const uint4*)&atb[(r0 + r) * DBI + k8];
    }
    if (tid < EROWS) {
        long g = r0 + tid;
        s_b[tid] = (int)(g / NF);
        float tc = tcont[g];
        float t0 = tc * ((float)TSW / 3000.0f);
        int lo0 = (int)t0; if (lo0 > TSW - 2) lo0 = TSW - 2; if (lo0 < 0) lo0 = 0;
        s_lo0[tid] = lo0; s_w0[tid] = t0 - (float)lo0;
        float t1 = tc * ((float)TS1 / 3000.0f);
        int lo1 = (int)t1; if (lo1 > TS1 - 2) lo1 = TS1 - 2; if (lo1 < 0) lo1 = 0;
        s_lo1[tid] = lo1; s_w1[tid] = t1 - (float)lo1;
    }
    __syncthreads();
    int mrow = lane & 15, quad = lane >> 4;
    // ---- Phase 1: film GEMM (gamma+beta, 2 m-tiles); wave owns 6 nt -> X[:,128:512] bf16
    for (int i = 0; i < 6; ++i) {
        int nt = wave + 4 * i;
        f32x4 ag0 = {0,0,0,0}, ab0 = {0,0,0,0}, ag1 = {0,0,0,0}, ab1 = {0,0,0,0};
        #pragma unroll
        for (int kt = 0; kt < 4; ++kt) {
            bf16x8 a0 = *(const bf16x8*)&X[mrow][kt * 32 + quad * 8];
            bf16x8 a1 = *(const bf16x8*)&X[mrow + 16][kt * 32 + quad * 8];
            bf16x8 bg = *(const bf16x8*)&Wg[(((nt * 4 + kt) * 64) + lane) * 8];
            bf16x8 bb = *(const bf16x8*)&Wb[(((nt * 4 + kt) * 64) + lane) * 8];
            ag0 = __builtin_amdgcn_mfma_f32_16x16x32_bf16(a0, bg, ag0, 0, 0, 0);
            ab0 = __builtin_amdgcn_mfma_f32_16x16x32_bf16(a0, bb, ab0, 0, 0, 0);
            ag1 = __builtin_amdgcn_mfma_f32_16x16x32_bf16(a1, bg, ag1, 0, 0, 0);
            ab1 = __builtin_amdgcn_mfma_f32_16x16x32_bf16(a1, bb, ab1, 0, 0, 0);
        }
        int c = nt * 16 + mrow;
        bool sel = c >= DSW;
        int cc = sel ? c - DSW : c;
        const float* S = sel ? src1 : src0;
        int Ts = sel ? TS1 : TSW;
        float gb = gbias[c], bbv = bbias[c];
        #pragma unroll
        for (int q = 0; q < 4; ++q) {
            {
                int r = quad * 4 + q;
                int b = s_b[r];
                int lo = sel ? s_lo1[r] : s_lo0[r];
                float w = sel ? s_w1[r] : s_w0[r];
                const float* Sp = S + ((long)b * Ts + lo) * DSW + cc;
                float pv = (1.0f - w) * Sp[0] + w * Sp[DSW];
                X[r][128 + c] = f2bf((ag0[q] + gb) * pv + (ab0[q] + bbv));
            }
            {
                int r = quad * 4 + q + 16;
                int b = s_b[r];
                int lo = sel ? s_lo1[r] : s_lo0[r];
                float w = sel ? s_w1[r] : s_w0[r];
                const float* Sp = S + ((long)b * Ts + lo) * DSW + cc;
                float pv = (1.0f - w) * Sp[0] + w * Sp[DSW];
                X[r][128 + c] = f2bf((ag1[q] + gb) * pv + (ab1[q] + bbv));
            }
        }
    }
    __syncthreads();
    // ---- Phase 2: embs[32,512] = X[32,512] @ W2 + bias2 ; wave owns 8 n-tiles x 2 m-tiles
    f32x4 acc[2][8];
    #pragma unroll
    for (int h = 0; h < 2; ++h)
        #pragma unroll
        for (int n = 0; n < 8; ++n) acc[h][n] = (f32x4){0, 0, 0, 0};
    for (int kt = 0; kt < 16; ++kt) {
        bf16x8 a0 = *(const bf16x8*)&X[mrow][kt * 32 + quad * 8];
        bf16x8 a1 = *(const bf16x8*)&X[mrow + 16][kt * 32 + quad * 8];
        #pragma unroll
        for (int n = 0; n < 8; ++n) {
            int nt = wave * 8 + n;
            bf16x8 bfv = *(const bf16x8*)&W2[((nt * 16 + kt) * 64 + lane) * 8];
            acc[0][n] = __builtin_amdgcn_mfma_f32_16x16x32_bf16(a0, bfv, acc[0][n], 0, 0, 0);
            acc[1][n] = __builtin_amdgcn_mfma_f32_16x16x32_bf16(a1, bfv, acc[1][n], 0, 0, 0);
        }
    }
    #pragma unroll
    for (int n = 0; n < 8; ++n) {
        int cbase = (wave * 8 + n) * 16 + mrow;
        float bv = bias2[cbase];
        #pragma unroll
        for (int q = 0; q < 4; ++q) {
            embs[(r0 + quad * 4 + q) * DMODEL + cbase] = acc[0][n][q] + bv;
            embs[(r0 + 16 + quad * 4 + q) * DMODEL + cbase] = acc[1][n][q] + bv;
        }
    }
}

extern "C" void kernel_launch(void* const* d_in, const int* in_sizes, int n_in,
                              void* d_out, int out_size, void* d_ws, size_t ws_size,
                              hipStream_t stream)
{
    const float* fs     = (const float*)d_in[0];
    const float* src0   = (const float*)d_in[1];
    const float* src1   = (const float*)d_in[2];
    const int*   tlen   = (const int*)d_in[3];
    const float* conv_w = (const float*)d_in[4];
    const float* ln_g   = (const float*)d_in[5];
    const float* ln_b   = (const float*)d_in[6];
    const float* wp_w   = (const float*)d_in[7];
    const float* wp_b   = (const float*)d_in[8];
    const float* f0w    = (const float*)d_in[9];
    const float* f0b    = (const float*)d_in[10];
    const float* f1w    = (const float*)d_in[11];
    const float* f1b    = (const float*)d_in[12];
    const float* tw     = (const float*)d_in[13];
    const float* tb     = (const float*)d_in[14];
    const float* aw     = (const float*)d_in[15];
    const float* apb    = (const float*)d_in[16];
    const float* bw     = (const float*)d_in[17];
    const float* bpb    = (const float*)d_in[18];

    float* embs  = (float*)d_out;
    float* alpha = embs + (long)BQ * NF * DMODEL;
    float* qtyo  = alpha + (long)BQ * TBI;

    char* ws = (char*)d_ws;
    size_t off = 0;
    unsigned short* at = (unsigned short*)(ws + off); off += 4915200;   // [B,NF,128] bf16
    float2* c2     = (float2*)(ws + off); off += 1536000;
    float*  tcont  = (float*)(ws + off);  off += 76800;
    int*    ffA    = (int*)(ws + off);    off += 76800;
    float2* params = (float2*)(ws + off); off += 512;
    unsigned short* Wg = (unsigned short*)(ws + off); off += 98304;
    unsigned short* Wb = (unsigned short*)(ws + off); off += 98304;
    unsigned short* W2 = (unsigned short*)(ws + off); off += 524288;
    float* gbias = (float*)(ws + off); off += 1536;
    float* bbias = (float*)(ws + off); off += 1536;
    float* bias2 = (float*)(ws + off); off += 2048;

    k_alpha_prep<<<ALPHA_BLOCKS + 1217, 256, 0, stream>>>(
        fs, conv_w, ln_g, ln_b, wp_w, wp_b, alpha,
        f0w, f1w, tw, aw, bw, f0b, f1b, tb, apb, bpb,
        Wg, Wb, W2, gbias, bbias, bias2, qtyo);
    k_scan4<<<BQ, 1024, 0, stream>>>(alpha, tlen, params, qtyo, c2, tcont, ffA);
    k_cif5<<<(BQ * NF) / 4, 256, 0, stream>>>(fs, c2, ffA, params, at);
    k_emb9<<<(BQ * NF) / EROWS, 256, 0, stream>>>(at, tcont, src0, src1,
                                                  Wg, Wb, W2, gbias, bbias, bias2, embs);
}

// Round 13
// 262.323 us; speedup vs baseline: 1.0902x; 1.0142x over previous
//
#include <hip/hip_runtime.h>
#include <math.h>

#define BQ 64
#define TBI 3000
#define DBI 128
#define TSW 375
#define TS1 188
#define DSW 192
#define NF 300
#define DMODEL 512
#define EPSLN 1e-5f

typedef __bf16 bf16x8 __attribute__((ext_vector_type(8)));
typedef float f32x4 __attribute__((ext_vector_type(4)));

__device__ __forceinline__ unsigned short f2bf(float f) {
    unsigned u = __float_as_uint(f);
    unsigned r = (u + 0x7FFFu + ((u >> 16) & 1u)) >> 16;
    return (unsigned short)r;
}

#define ALPHA_BLOCKS 24000   // (BQ*TBI)/8

// ---------------- Kernel A+prep merged. Alpha row-math: single 5-step butterfly over
// 5 independent partials (s, q2, s3, c1, c2) instead of 3 sequential butterflies —
// shuffle-chain depth 15 -> 5. var = q2/128 - mu^2; z = rs*(s3 - mu*c1) + c2 + b.
// Exact-arithmetic-equivalent, differently rounded (absmax expected to shift).
__global__ __launch_bounds__(256) void k_alpha_prep(
    const float* __restrict__ fs, const float* __restrict__ conv_w,
    const float* __restrict__ ln_g, const float* __restrict__ ln_b,
    const float* __restrict__ wp_w, const float* __restrict__ wp_b,
    float* __restrict__ alpha_out,
    const float* __restrict__ f0w, const float* __restrict__ f1w,
    const float* __restrict__ tw, const float* __restrict__ aw, const float* __restrict__ bw,
    const float* __restrict__ f0b, const float* __restrict__ f1b,
    const float* __restrict__ tb, const float* __restrict__ apb, const float* __restrict__ bpb,
    unsigned short* __restrict__ Wg, unsigned short* __restrict__ Wb,
    unsigned short* __restrict__ W2,
    float* __restrict__ gbias, float* __restrict__ bbias, float* __restrict__ bias2,
    float* __restrict__ qtyo)
{
    if (blockIdx.x >= ALPHA_BLOCKS) {
        int pbid = blockIdx.x - ALPHA_BLOCKS;
        if (pbid == 1216) {
            for (int c = threadIdx.x; c < 512; c += 256) {
                if (c < 384) {
                    gbias[c] = c < 192 ? f0b[c] : f1b[c - 192];
                    bbias[c] = c < 192 ? f0b[c + 192] : f1b[c - 192 + 192];
                }
                bias2[c] = tb[c] + apb[c] + bpb[c];
            }
            if (threadIdx.x == 0) qtyo[0] = 0.f;
            return;
        }
        int i = pbid * 256 + threadIdx.x;
        if (i < 49152) {                       // film gamma/beta: K=128 (KT=4), N=384 (NT=24)
            int j = i & 7, lane = (i >> 3) & 63, kt = (i >> 9) & 3, nt = i >> 11;
            int k = kt * 32 + (lane >> 4) * 8 + j;
            int n = nt * 16 + (lane & 15);
            float g, b;
            if (n < 192) { g = f0w[k * 384 + n];         b = f0w[k * 384 + n + 192]; }
            else         { g = f1w[k * 384 + (n - 192)]; b = f1w[k * 384 + (n - 192) + 192]; }
            Wg[i] = f2bf(g); Wb[i] = f2bf(b);
        } else {                               // W2 stacked [tw;aw;bw]: K=512 (KT=16), N=512 (NT=32)
            int ii = i - 49152;
            int j = ii & 7, lane = (ii >> 3) & 63, kt = (ii >> 9) & 15, nt = ii >> 13;
            int k = kt * 32 + (lane >> 4) * 8 + j;
            int n = nt * 16 + (lane & 15);
            float v;
            if (k < 128)      v = tw[k * 512 + n];
            else if (k < 320) v = aw[(k - 128) * 512 + n];
            else              v = bw[(k - 320) * 512 + n];
            W2[ii] = f2bf(v);
        }
        return;
    }
    int wave = threadIdx.x >> 6, lane = threadIdx.x & 63;
    int l = lane & 31;
    long g = (long)blockIdx.x * 8 + wave * 2 + (lane >> 5);
    const float* row = fs + g * DBI;
    float4 f  = *(const float4*)&row[4 * l];
    float4 cw = *(const float4*)&conv_w[4 * l];
    float4 lg = *(const float4*)&ln_g[4 * l];
    float4 lb = *(const float4*)&ln_b[4 * l];
    float4 wp = *(const float4*)&wp_w[4 * l];
    float4 x; x.x = f.x * cw.x; x.y = f.y * cw.y; x.z = f.z * cw.z; x.w = f.w * cw.w;
    float4 gw; gw.x = lg.x * wp.x; gw.y = lg.y * wp.y; gw.z = lg.z * wp.z; gw.w = lg.w * wp.w;
    float s  = x.x + x.y + x.z + x.w;
    float q2 = x.x * x.x + x.y * x.y + x.z * x.z + x.w * x.w;
    float s3 = x.x * gw.x + x.y * gw.y + x.z * gw.z + x.w * gw.w;
    float c1 = gw.x + gw.y + gw.z + gw.w;
    float c2 = lb.x * wp.x + lb.y * wp.y + lb.z * wp.z + lb.w * wp.w;
    for (int m = 16; m >= 1; m >>= 1) {        // ONE butterfly, 5 independent values
        s  += __shfl_xor(s,  m, 64);
        q2 += __shfl_xor(q2, m, 64);
        s3 += __shfl_xor(s3, m, 64);
        c1 += __shfl_xor(c1, m, 64);
        c2 += __shfl_xor(c2, m, 64);
    }
    float mu = s * (1.0f / 128.0f);
    float var = q2 * (1.0f / 128.0f) - mu * mu;
    float rs = rsqrtf(var + EPSLN);
    float z = rs * (s3 - mu * c1) + c2 + wp_b[0];
    float a = 4.0f / (1.0f + expf(-z));
    if (l == 0) alpha_out[g] = a;
}

// ---------------- Kernel B: sums (f64, wave-shuffle) + scan + searchsorted + ff + qty
__global__ __launch_bounds__(1024) void k_scan4(
    const float* __restrict__ alpha, const int* __restrict__ tlen,
    float2* __restrict__ params, float* __restrict__ qtyo,
    float2* __restrict__ c2, float* __restrict__ tcont, int* __restrict__ ffout)
{
    __shared__ float2 sc[TBI];
    __shared__ float2 part[2][1024];
    __shared__ double wpart[16];
    int b = blockIdx.x, tid = threadIdx.x;
    int wv = tid >> 6, ln = tid & 63;
    const float* ar = alpha + (long)b * TBI;
    double s = 0.0;
    for (int t = tid; t < TBI; t += 1024) s += (double)ar[t];
    for (int m = 32; m >= 1; m >>= 1) s += __shfl_xor(s, m, 64);
    if (ln == 0) wpart[wv] = s;
    __syncthreads();
    if (wv == 0) {
        double d = (ln < 16) ? wpart[ln] : 0.0;
        for (int m = 8; m >= 1; m >>= 1) d += __shfl_xor(d, m, 64);
        if (ln == 0) wpart[0] = d;
    }
    __syncthreads();
    double sum_a = wpart[0];
    __syncthreads();
    double tgt = (double)tlen[b];
    double sa = sum_a < 1e-8 ? 1e-8 : sum_a;
    float r = (float)(tgt / sa);
    double s2 = 0.0;
    for (int t = tid; t < TBI; t += 1024) s2 += (double)(ar[t] * r);
    for (int m = 32; m >= 1; m >>= 1) s2 += __shfl_xor(s2, m, 64);
    if (ln == 0) wpart[wv] = s2;
    __syncthreads();
    if (wv == 0) {
        double d = (ln < 16) ? wpart[ln] : 0.0;
        for (int m = 8; m >= 1; m >>= 1) d += __shfl_xor(d, m, 64);
        if (ln == 0) wpart[0] = d;
    }
    __syncthreads();
    float sum_cif = (float)wpart[0];
    float cs = ceilf(sum_cif); if (cs < 1.0f) cs = 1.0f;
    float thr = sum_cif / cs;
    float rthr = 1.0f / thr;
    if (tid == 0) {
        params[b] = make_float2(r, thr);
        atomicAdd(qtyo, (float)fabs(sum_a - tgt) * (1.0f / (float)BQ));
    }
    // ---- scan: byte-identical Hillis-Steele (feeds searchsorted boundaries)
    int base = tid * 3;
    float2 run = make_float2(0.f, 0.f);
    if (base < TBI) {
        for (int j = 0; j < 3; ++j) {
            int t = base + j;
            float ac = ar[t] * r;
            run.x += ac * rthr; run.y += ac;
            sc[t] = run;
        }
    }
    part[0][tid] = (base < TBI) ? run : make_float2(0.f, 0.f);
    __syncthreads();
    int srcb = 0;
    for (int d = 1; d < 1024; d <<= 1) {
        float2 v = part[srcb][tid];
        if (tid >= d) { float2 u = part[srcb][tid - d]; v.x += u.x; v.y += u.y; }
        part[srcb ^ 1][tid] = v;
        srcb ^= 1;
        __syncthreads();
    }
    if (base < TBI && tid > 0) {
        float2 off = part[srcb][tid - 1];
        for (int j = 0; j < 3; ++j) { sc[base + j].x += off.x; sc[base + j].y += off.y; }
    }
    __syncthreads();
    for (int t = tid; t < TBI; t += 1024) {
        float ac = ar[t] * r;
        c2[(long)b * TBI + t] = make_float2(sc[t].x, ac);
    }
    if (tid < NF) {
        float v = (float)(tid + 1) * thr;
        int lo = 0, hi = TBI;
        while (lo < hi) { int mid = (lo + hi) >> 1; if (sc[mid].y < v) lo = mid + 1; else hi = mid; }
        int ff = lo; if (ff > TBI - 1) ff = TBI - 1;
        ffout[b * NF + tid] = ff;
        int tl = ff - 1; if (tl < 0) tl = 0;
        float cum_at = sc[tl].y;
        float a_at = ar[ff] * r;
        if (a_at < 1e-8f) a_at = 1e-8f;
        float tc = (float)tl + (v - cum_at) / a_at;
        tc = fminf(fmaxf(tc, 0.0f), (float)(TBI - 1));
        tcont[b * NF + tid] = tc;
    }
}

// ---------------- Kernel D: CIF, one wave per token; 2-frame unrolled (same accum order)
__global__ __launch_bounds__(256) void k_cif5(
    const float* __restrict__ fs, const float2* __restrict__ c2,
    const int* __restrict__ ffA, const float2* __restrict__ params,
    unsigned short* __restrict__ at)
{
    int wid = threadIdx.x >> 6, lane = threadIdx.x & 63;
    int wg = blockIdx.x * 4 + wid;          // 0..19199
    int b = wg / NF, j = wg - b * NF;
    const int* ffb = ffA + b * NF;
    int s = (j == 0) ? 0 : ffb[j - 1];
    int e = (j == NF - 1) ? (TBI - 1) : ffb[j];
    float thr = params[b].y;
    float rthr = 1.0f / thr;
    const float2* cb = c2 + (long)b * TBI;
    const float* fb = fs + (long)b * TBI * DBI;
    float a0 = 0.f, a1 = 0.f;
    #define CIF_BODY(T) do { \
        float2 v = cb[T]; \
        float2 h = *(const float2*)&fb[(long)(T) * DBI + 2 * lane]; \
        float c = v.x, ac = v.y; \
        float av = ac * rthr; \
        float prev = c - av; \
        float kp = floorf(prev), kc = floorf(c); \
        bool fired = kc > kp; \
        float w_lo = fired ? (kp + 1.0f - prev) * thr : ac; \
        float w_hi = fired ? (c - kc) * thr : 0.0f; \
        int ip = (int)kp; if (ip > NF - 1) ip = NF - 1; if (ip < 0) ip = 0; \
        int ic = (int)kc; if (ic > NF - 1) ic = NF - 1; if (ic < 0) ic = 0; \
        if (ip == j) { a0 += w_lo * h.x; a1 += w_lo * h.y; } \
        if (fired && ic == j) { a0 += w_hi * h.x; a1 += w_hi * h.y; } \
    } while (0)
    int t = s;
    for (; t + 1 <= e; t += 2) { CIF_BODY(t); CIF_BODY(t + 1); }
    if (t <= e) CIF_BODY(t);
    #undef CIF_BODY
    unsigned short* ab = at + (long)b * NF * DBI;
    *(unsigned*)&ab[j * DBI + 2 * lane] = (unsigned)f2bf(a0) | ((unsigned)f2bf(a1) << 16);
}

// ---------------- Kernel E (MFMA): FiLM + interp + projections; EROWS=32, 600 blocks,
// 256 threads (4 waves), launch_bounds(256,3). Measured-best emb config.
#define EROWS 32
__global__ __launch_bounds__(256, 3) void k_emb9(
    const unsigned short* __restrict__ atb, const float* __restrict__ tcont,
    const float* __restrict__ src0, const float* __restrict__ src1,
    const unsigned short* __restrict__ Wg, const unsigned short* __restrict__ Wb,
    const unsigned short* __restrict__ W2,
    const float* __restrict__ gbias, const float* __restrict__ bbias,
    const float* __restrict__ bias2, float* __restrict__ embs)
{
    __shared__ __align__(16) unsigned short X[EROWS][520];
    __shared__ float s_w0[EROWS], s_w1[EROWS];
    __shared__ int s_lo0[EROWS], s_lo1[EROWS], s_b[EROWS];
    int tid = threadIdx.x;
    int wave = tid >> 6, lane = tid & 63;
    long r0 = (long)blockIdx.x * EROWS;
    for (int idx = tid; idx < 512; idx += 256) {   // 32 rows x 16 chunks of 8 bf16
        int r = idx >> 4, k8 = (idx & 15) * 8;
        *(uint4*)&X[r][k8] = *(const uint4*)&atb[(r0 + r) * DBI + k8];
    }
    if (tid < EROWS) {
        long g = r0 + tid;
        s_b[tid] = (int)(g / NF);
        float tc = tcont[g];
        float t0 = tc * ((float)TSW / 3000.0f);
        int lo0 = (int)t0; if (lo0 > TSW - 2) lo0 = TSW - 2; if (lo0 < 0) lo0 = 0;
        s_lo0[tid] = lo0; s_w0[tid] = t0 - (float)lo0;
        float t1 = tc * ((float)TS1 / 3000.0f);
        int lo1 = (int)t1; if (lo1 > TS1 - 2) lo1 = TS1 - 2; if (lo1 < 0) lo1 = 0;
        s_lo1[tid] = lo1; s_w1[tid] = t1 - (float)lo1;
    }
    __syncthreads();
    int mrow = lane & 15, quad = lane >> 4;
    // ---- Phase 1: film GEMM (gamma+beta, 2 m-tiles); wave owns 6 nt -> X[:,128:512] bf16
    for (int i = 0; i < 6; ++i) {
        int nt = wave + 4 * i;
        f32x4 ag0 = {0,0,0,0}, ab0 = {0,0,0,0}, ag1 = {0,0,0,0}, ab1 = {0,0,0,0};
        #pragma unroll
        for (int kt = 0; kt < 4; ++kt) {
            bf16x8 a0 = *(const bf16x8*)&X[mrow][kt * 32 + quad * 8];
            bf16x8 a1 = *(const bf16x8*)&X[mrow + 16][kt * 32 + quad * 8];
            bf16x8 bg = *(const bf16x8*)&Wg[(((nt * 4 + kt) * 64) + lane) * 8];
            bf16x8 bb = *(const bf16x8*)&Wb[(((nt * 4 + kt) * 64) + lane) * 8];
            ag0 = __builtin_amdgcn_mfma_f32_16x16x32_bf16(a0, bg, ag0, 0, 0, 0);
            ab0 = __builtin_amdgcn_mfma_f32_16x16x32_bf16(a0, bb, ab0, 0, 0, 0);
            ag1 = __builtin_amdgcn_mfma_f32_16x16x32_bf16(a1, bg, ag1, 0, 0, 0);
            ab1 = __builtin_amdgcn_mfma_f32_16x16x32_bf16(a1, bb, ab1, 0, 0, 0);
        }
        int c = nt * 16 + mrow;
        bool sel = c >= DSW;
        int cc = sel ? c - DSW : c;
        const float* S = sel ? src1 : src0;
        int Ts = sel ? TS1 : TSW;
        float gb = gbias[c], bbv = bbias[c];
        #pragma unroll
        for (int q = 0; q < 4; ++q) {
            {
                int r = quad * 4 + q;
                int b = s_b[r];
                int lo = sel ? s_lo1[r] : s_lo0[r];
                float w = sel ? s_w1[r] : s_w0[r];
                const float* Sp = S + ((long)b * Ts + lo) * DSW + cc;
                float pv = (1.0f - w) * Sp[0] + w * Sp[DSW];
                X[r][128 + c] = f2bf((ag0[q] + gb) * pv + (ab0[q] + bbv));
            }
            {
                int r = quad * 4 + q + 16;
                int b = s_b[r];
                int lo = sel ? s_lo1[r] : s_lo0[r];
                float w = sel ? s_w1[r] : s_w0[r];
                const float* Sp = S + ((long)b * Ts + lo) * DSW + cc;
                float pv = (1.0f - w) * Sp[0] + w * Sp[DSW];
                X[r][128 + c] = f2bf((ag1[q] + gb) * pv + (ab1[q] + bbv));
            }
        }
    }
    __syncthreads();
    // ---- Phase 2: embs[32,512] = X[32,512] @ W2 + bias2 ; wave owns 8 n-tiles x 2 m-tiles
    f32x4 acc[2][8];
    #pragma unroll
    for (int h = 0; h < 2; ++h)
        #pragma unroll
        for (int n = 0; n < 8; ++n) acc[h][n] = (f32x4){0, 0, 0, 0};
    for (int kt = 0; kt < 16; ++kt) {
        bf16x8 a0 = *(const bf16x8*)&X[mrow][kt * 32 + quad * 8];
        bf16x8 a1 = *(const bf16x8*)&X[mrow + 16][kt * 32 + quad * 8];
        #pragma unroll
        for (int n = 0; n < 8; ++n) {
            int nt = wave * 8 + n;
            bf16x8 bfv = *(const bf16x8*)&W2[((nt * 16 + kt) * 64 + lane) * 8];
            acc[0][n] = __builtin_amdgcn_mfma_f32_16x16x32_bf16(a0, bfv, acc[0][n], 0, 0, 0);
            acc[1][n] = __builtin_amdgcn_mfma_f32_16x16x32_bf16(a1, bfv, acc[1][n], 0, 0, 0);
        }
    }
    #pragma unroll
    for (int n = 0; n < 8; ++n) {
        int cbase = (wave * 8 + n) * 16 + mrow;
        float bv = bias2[cbase];
        #pragma unroll
        for (int q = 0; q < 4; ++q) {
            embs[(r0 + quad * 4 + q) * DMODEL + cbase] = acc[0][n][q] + bv;
            embs[(r0 + 16 + quad * 4 + q) * DMODEL + cbase] = acc[1][n][q] + bv;
        }
    }
}

extern "C" void kernel_launch(void* const* d_in, const int* in_sizes, int n_in,
                              void* d_out, int out_size, void* d_ws, size_t ws_size,
                              hipStream_t stream)
{
    const float* fs     = (const float*)d_in[0];
    const float* src0   = (const float*)d_in[1];
    const float* src1   = (const float*)d_in[2];
    const int*   tlen   = (const int*)d_in[3];
    const float* conv_w = (const float*)d_in[4];
    const float* ln_g   = (const float*)d_in[5];
    const float* ln_b   = (const float*)d_in[6];
    const float* wp_w   = (const float*)d_in[7];
    const float* wp_b   = (const float*)d_in[8];
    const float* f0w    = (const float*)d_in[9];
    const float* f0b    = (const float*)d_in[10];
    const float* f1w    = (const float*)d_in[11];
    const float* f1b    = (const float*)d_in[12];
    const float* tw     = (const float*)d_in[13];
    const float* tb     = (const float*)d_in[14];
    const float* aw     = (const float*)d_in[15];
    const float* apb    = (const float*)d_in[16];
    const float* bw     = (const float*)d_in[17];
    const float* bpb    = (const float*)d_in[18];

    float* embs  = (float*)d_out;
    float* alpha = embs + (long)BQ * NF * DMODEL;
    float* qtyo  = alpha + (long)BQ * TBI;

    char* ws = (char*)d_ws;
    size_t off = 0;
    unsigned short* at = (unsigned short*)(ws + off); off += 4915200;   // [B,NF,128] bf16
    float2* c2     = (float2*)(ws + off); off += 1536000;
    float*  tcont  = (float*)(ws + off);  off += 76800;
    int*    ffA    = (int*)(ws + off);    off += 76800;
    float2* params = (float2*)(ws + off); off += 512;
    unsigned short* Wg = (unsigned short*)(ws + off); off += 98304;
    unsigned short* Wb = (unsigned short*)(ws + off); off += 98304;
    unsigned short* W2 = (unsigned short*)(ws + off); off += 524288;
    float* gbias = (float*)(ws + off); off += 1536;
    float* bbias = (float*)(ws + off); off += 1536;
    float* bias2 = (float*)(ws + off); off += 2048;

    k_alpha_prep<<<ALPHA_BLOCKS + 1217, 256, 0, stream>>>(
        fs, conv_w, ln_g, ln_b, wp_w, wp_b, alpha,
        f0w, f1w, tw, aw, bw, f0b, f1b, tb, apb, bpb,
        Wg, Wb, W2, gbias, bbias, bias2, qtyo);
    k_scan4<<<BQ, 1024, 0, stream>>>(alpha, tlen, params, qtyo, c2, tcont, ffA);
    k_cif5<<<(BQ * NF) / 4, 256, 0, stream>>>(fs, c2, ffA, params, at);
    k_emb9<<<(BQ * NF) / EROWS, 256, 0, stream>>>(at, tcont, src0, src1,
                                                  Wg, Wb, W2, gbias, bbias, bias2, embs);
}